// Round 4
// baseline (731.842 us; speedup 1.0000x reference)
//
#include <hip/hip_runtime.h>
#include <stdint.h>

#define T_TOK 8192
#define K_IN  4096
#define O_OUT 6144

typedef __attribute__((ext_vector_type(4))) float f32x4;
typedef __attribute__((ext_vector_type(8))) int i32x8;
typedef unsigned int uint32;

// ---------- helpers ----------

__device__ inline void load_lds_16(const void* g, void* l) {
    __builtin_amdgcn_global_load_lds(
        (const __attribute__((address_space(1))) unsigned int*)g,
        (__attribute__((address_space(3))) unsigned int*)l, 16, 0, 0);
}

// pack 4 floats -> 4 fp8 e4m3 bytes (RNE, saturating), byte i = input i
__device__ inline int pack4_fp8(float a, float b, float c, float d) {
    int r = __builtin_amdgcn_cvt_pk_fp8_f32(a, b, 0, false);  // bytes 0,1
    r = __builtin_amdgcn_cvt_pk_fp8_f32(c, d, r, true);       // bytes 2,3
    return r;
}

// ---------- kernel 1: per-token dynamic fp8 quantization of x ----------
__global__ __launch_bounds__(256) void quant_x(const float* __restrict__ x,
                                               uint32* __restrict__ xq,
                                               float* __restrict__ xscale) {
    const int t   = blockIdx.x;
    const int tid = threadIdx.x;
    const float4* row4 = (const float4*)(x + (size_t)t * K_IN);

    float4 v[4];
    float amax = 0.f;
#pragma unroll
    for (int j = 0; j < 4; ++j) {
        v[j] = row4[tid + j * 256];
        amax = fmaxf(amax, fmaxf(fmaxf(fabsf(v[j].x), fabsf(v[j].y)),
                                 fmaxf(fabsf(v[j].z), fabsf(v[j].w))));
    }
#pragma unroll
    for (int off = 32; off > 0; off >>= 1)
        amax = fmaxf(amax, __shfl_down(amax, off, 64));
    __shared__ float red[4];
    if ((tid & 63) == 0) red[tid >> 6] = amax;
    __syncthreads();
    amax = fmaxf(fmaxf(red[0], red[1]), fmaxf(red[2], red[3]));

    const float scale = fmaxf(amax, 1e-12f) / 448.0f;
    if (tid == 0) xscale[t] = scale;

    uint32* orow = xq + (size_t)t * (K_IN / 4);
#pragma unroll
    for (int j = 0; j < 4; ++j) {
        // correctly-rounded fp32 division matches the reference's x / x_scale
        float q0 = v[j].x / scale, q1 = v[j].y / scale;
        float q2 = v[j].z / scale, q3 = v[j].w / scale;
        orow[tid + j * 256] = (uint32)pack4_fp8(q0, q1, q2, q3);  // coalesced dword
    }
}

// ---------- kernel 2: fp8 quantization of W (scale applied inside GEMM) ----------
__global__ __launch_bounds__(256) void quant_w(const float* __restrict__ w,
                                               uint32* __restrict__ wq) {
    const size_t u = (size_t)blockIdx.x * 256 + threadIdx.x;  // dword index
    float4 v = ((const float4*)w)[u];
    wq[u] = (uint32)pack4_fp8(v.x, v.y, v.z, v.w);
}

// ---------- kernel 3: fp8 MX GEMM, 128x128x128 tile, 4 waves, 3 blocks/CU ----
// A: [T][K] fp8 bytes, B: [O][K] fp8 bytes.
// C[t][o] = xs[t] * sum_kb s[o/128][kb] * (A.B)_kb   (Horner per K-tile)
//
// Occupancy thesis (rounds 0/1/3 all ~23% occ = 2 waves/SIMD and all ~26%
// MfmaUtil; m148's 3-wave/SIMD structure = 35% on the same MX instruction;
// 8-wave ubench = 95%): we are TLP/latency-bound. Buy wave #3:
//  * wave tile 64x64 (4x4 frags) -> acc = 64 AGPR (was 128)
//  * B global->VGPR single-buffered (32 VGPR, issued first in the body so
//    L2 latency hides under STAGE/Horner/first ds_reads)
//  * A-only LDS 2-slot ring (2 x 16 KB) - LDS no longer occupancy-binding
//  * __launch_bounds__(256,3): force >=3 waves/SIMD register allocation
// Everything else (swizzle, fragment layout, Horner, epilogue) carried over
// from the passing round-3 kernel, re-parameterized to BM=BN=128.
__global__ __launch_bounds__(256, 3) void gemm_fp8(const unsigned char* __restrict__ A,
                                                   const unsigned char* __restrict__ B,
                                                   const float* __restrict__ sinv,
                                                   const float* __restrict__ xscale,
                                                   float* __restrict__ C) {
    constexpr int BM = 128, BN = 128, BK = 128;
    constexpr int NKB = K_IN / BK;  // 32 K-tiles, one weight-scale block each
    extern __shared__ unsigned char smem[];  // 32 KB: A ring, slot c -> smem + (c&1)*16384

    const int bn  = blockIdx.x;      // 48 o-tiles == one o scale-block each
    const int bm  = blockIdx.y;      // 64 token tiles
    const int tid = threadIdx.x;
    const int lane = tid & 63;
    const int wv   = tid >> 6;
    const int wm   = (wv >> 1) * 64;    // wave M offset in tile
    const int wn   = (wv & 1) * 64;     // wave N offset in tile
    const int G2   = (lane >> 4) * 2;   // k-chunk pair for this lane group

    // ---- A staging: linear LDS dest (gload_lds lane rule), swizzle on the
    //      GLOBAL source chunk index (rule #21). Row r holds chunk j^(r&7) in slot j.
    const int tr = tid >> 3;                  // 32 rows per 4 KB round
    const int kc = (tid & 7) ^ (tr & 7);
    const unsigned char* Ag = A + (size_t)(bm * BM + tr) * K_IN + kc * 16;
    const int ldst = tid * 16;

    // ---- A fragment-read constants (r&7 == lane&7 for all fragment rows)
    const int rA  = lane & 15;
    const int cs0 = ((G2    ) ^ (lane & 7)) * 16;
    const int cs1 = ((G2 + 1) ^ (lane & 7)) * 16;

    // ---- B fragment global base: frag j = row bn*BN+wn+j*16+rA,
    //      bytes kb*128 + G2*16 .. +31 (byte-identical to the old LDS path)
    const unsigned char* Bg = B + (size_t)(bn * BN + wn + rA) * K_IN + G2 * 16;

    const float* srow = sinv + (size_t)bn * NKB;   // BN==128: one scale row per bn

    union F { i32x8 v; int4 h[2]; };
    f32x4 acc[4][4] = {};
    float s_prev = srow[0];

// stage A chunk ck into ring slot ck&1 (4 x gload_lds, 32-row strides; &31
// wraps the tail prefetch onto valid memory - that slot is never read)
#define STAGE(ck_) {                                                         \
    unsigned char* d_ = smem + (size_t)((ck_) & 1) * 16384 + ldst;           \
    const unsigned char* g_ = Ag + (size_t)((ck_) & 31) * BK;                \
    load_lds_16(g_,                      d_);                                \
    load_lds_16(g_ + (size_t) 32 * K_IN, d_ +  4096);                        \
    load_lds_16(g_ + (size_t) 64 * K_IN, d_ +  8192);                        \
    load_lds_16(g_ + (size_t) 96 * K_IN, d_ + 12288); }

// load the 4 B fragments of K-tile ck into regs (8 x global_load_dwordx4)
#define LOADB(dst_, ck_) {                                                   \
    const unsigned char* g_ = Bg + (size_t)(ck_) * BK;                       \
    dst_[0].h[0] = *(const int4*)(g_);                                       \
    dst_[0].h[1] = *(const int4*)(g_ + 16);                                  \
    dst_[1].h[0] = *(const int4*)(g_ + (size_t)16 * K_IN);                   \
    dst_[1].h[1] = *(const int4*)(g_ + (size_t)16 * K_IN + 16);              \
    dst_[2].h[0] = *(const int4*)(g_ + (size_t)32 * K_IN);                   \
    dst_[2].h[1] = *(const int4*)(g_ + (size_t)32 * K_IN + 16);              \
    dst_[3].h[0] = *(const int4*)(g_ + (size_t)48 * K_IN);                   \
    dst_[3].h[1] = *(const int4*)(g_ + (size_t)48 * K_IN + 16); }

#define LDA(d_, i_, pA_) {                                                   \
    const unsigned char* q_ = (pA_) + (wm + (i_) * 16 + rA) * 128;           \
    (d_).h[0] = *(const int4*)(q_ + cs0);                                    \
    (d_).h[1] = *(const int4*)(q_ + cs1); }

#define MFMA(i_, j_, af_, bf_)                                               \
    acc[i_][j_] = __builtin_amdgcn_mfma_scale_f32_16x16x128_f8f6f4(          \
        (af_).v, (bf_).v, acc[i_][j_], 0 /*A=fp8*/, 0 /*B=fp8*/,             \
        0, 0x7f7f7f7f, 0, 0x7f7f7f7f);

    // ---- prologue: stage A chunk 0; barrier publishes it.
    STAGE(0);
    __syncthreads();

    for (int kb = 0; kb < NKB; ++kb) {
        const unsigned char* pA = smem + (size_t)(kb & 1) * 16384;
        const float s_cur = srow[kb];
        const float rr = s_prev / s_cur;   // exactly 1.0 at kb==0
        s_prev = s_cur;

        F b[4];
        LOADB(b, kb);        // issue first: L2 latency hides under stage+Horner+LDA
        STAGE(kb + 1);       // prefetch next A chunk into the other slot

        // Horner rescale in the B-load shadow
#pragma unroll
        for (int i = 0; i < 4; ++i) {
            acc[i][0] *= rr; acc[i][1] *= rr;
            acc[i][2] *= rr; acc[i][3] *= rr;
        }

        __builtin_amdgcn_s_setprio(1);
#pragma unroll
        for (int i = 0; i < 4; ++i) {
            F af; LDA(af, i, pA);
            MFMA(i, 0, af, b[0]); MFMA(i, 1, af, b[1]);
            MFMA(i, 2, af, b[2]); MFMA(i, 3, af, b[3]);
        }
        __builtin_amdgcn_s_setprio(0);
        // single barrier per K-tile: drains the STAGE DMA (full body of MFMA
        // cover, ~1700 cy >= 900 cy HBM) and publishes slot (kb+1)&1.
        __syncthreads();
    }

    // epilogue: D col=lane&15, row=(lane>>4)*4+reg; final scale = s_last * xs[token]
#pragma unroll
    for (int i = 0; i < 4; ++i) {
#pragma unroll
        for (int r = 0; r < 4; ++r) {
            const int m_g = bm * BM + wm + i * 16 + (lane >> 4) * 4 + r;
            const float f = xscale[m_g] * s_prev;
            float* crow = C + (size_t)m_g * O_OUT + bn * BN + wn;
#pragma unroll
            for (int j = 0; j < 4; ++j)
                crow[j * 16 + (lane & 15)] = acc[i][j][r] * f;
        }
    }
#undef STAGE
#undef LOADB
#undef LDA
#undef MFMA
}

// ---------- launch ----------
extern "C" void kernel_launch(void* const* d_in, const int* in_sizes, int n_in,
                              void* d_out, int out_size, void* d_ws, size_t ws_size,
                              hipStream_t stream) {
    const float* x    = (const float*)d_in[0];
    const float* w    = (const float*)d_in[1];
    const float* sinv = (const float*)d_in[2];
    float* out = (float*)d_out;

    char* ws = (char*)d_ws;
    uint32* xq = (uint32*)ws;                                   // 32 MB (fp8 bytes)
    uint32* wq = (uint32*)(ws + (size_t)T_TOK * K_IN);          // 24 MB
    float* xscale = (float*)(ws + (size_t)T_TOK * K_IN
                                + (size_t)O_OUT * K_IN);        // 32 KB

    quant_x<<<T_TOK, 256, 0, stream>>>(x, xq, xscale);
    quant_w<<<(O_OUT * K_IN) / (4 * 256), 256, 0, stream>>>(w, wq);
    dim3 grid(O_OUT / 128, T_TOK / 128);   // (48, 64)
    gemm_fp8<<<grid, 256, 32768 /*dynamic LDS: 2-slot A ring*/, stream>>>(
        (const unsigned char*)xq, (const unsigned char*)wq, sinv, xscale, out);
}

// Round 5
// 595.484 us; speedup vs baseline: 1.2290x; 1.2290x over previous
//
#include <hip/hip_runtime.h>
#include <stdint.h>

#define T_TOK 8192
#define K_IN  4096
#define O_OUT 6144

typedef __attribute__((ext_vector_type(4))) float f32x4;
typedef __attribute__((ext_vector_type(8))) int i32x8;
typedef unsigned int uint32;

// ---------- helpers ----------

__device__ inline void load_lds_16(const void* g, void* l) {
    __builtin_amdgcn_global_load_lds(
        (const __attribute__((address_space(1))) unsigned int*)g,
        (__attribute__((address_space(3))) unsigned int*)l, 16, 0, 0);
}

// pack 4 floats -> 4 fp8 e4m3 bytes (RNE, saturating), byte i = input i
__device__ inline int pack4_fp8(float a, float b, float c, float d) {
    int r = __builtin_amdgcn_cvt_pk_fp8_f32(a, b, 0, false);  // bytes 0,1
    r = __builtin_amdgcn_cvt_pk_fp8_f32(c, d, r, true);       // bytes 2,3
    return r;
}

// ---------- kernel 1: per-token dynamic fp8 quantization of x ----------
__global__ __launch_bounds__(256) void quant_x(const float* __restrict__ x,
                                               uint32* __restrict__ xq,
                                               float* __restrict__ xscale) {
    const int t   = blockIdx.x;
    const int tid = threadIdx.x;
    const float4* row4 = (const float4*)(x + (size_t)t * K_IN);

    float4 v[4];
    float amax = 0.f;
#pragma unroll
    for (int j = 0; j < 4; ++j) {
        v[j] = row4[tid + j * 256];
        amax = fmaxf(amax, fmaxf(fmaxf(fabsf(v[j].x), fabsf(v[j].y)),
                                 fmaxf(fabsf(v[j].z), fabsf(v[j].w))));
    }
#pragma unroll
    for (int off = 32; off > 0; off >>= 1)
        amax = fmaxf(amax, __shfl_down(amax, off, 64));
    __shared__ float red[4];
    if ((tid & 63) == 0) red[tid >> 6] = amax;
    __syncthreads();
    amax = fmaxf(fmaxf(red[0], red[1]), fmaxf(red[2], red[3]));

    const float scale = fmaxf(amax, 1e-12f) / 448.0f;
    if (tid == 0) xscale[t] = scale;

    uint32* orow = xq + (size_t)t * (K_IN / 4);
#pragma unroll
    for (int j = 0; j < 4; ++j) {
        // correctly-rounded fp32 division matches the reference's x / x_scale
        float q0 = v[j].x / scale, q1 = v[j].y / scale;
        float q2 = v[j].z / scale, q3 = v[j].w / scale;
        orow[tid + j * 256] = (uint32)pack4_fp8(q0, q1, q2, q3);  // coalesced dword
    }
}

// ---------- kernel 2: fp8 quantization of W (scale applied inside GEMM) ----------
__global__ __launch_bounds__(256) void quant_w(const float* __restrict__ w,
                                               uint32* __restrict__ wq) {
    const size_t u = (size_t)blockIdx.x * 256 + threadIdx.x;  // dword index
    float4 v = ((const float4*)w)[u];
    wq[u] = (uint32)pack4_fp8(v.x, v.y, v.z, v.w);
}

// ---------- kernel 3: fp8 MX GEMM, 256x256x128, 8 waves, counted-vmcnt 4-phase ----
// A: [T][K] fp8 bytes, B: [O][K] fp8 bytes.
// C[t][o] = xs[t] * sum_kb s[o/128][kb] * (A.B)_kb   (Horner per K-tile)
//
// T3+T4+T5 (m201/m218): per K-tile 4 phases {ds_read quadrant frags | issue
// staged 8KB units of kb+1 -> barrier -> lgkmcnt(0) -> setprio(1) 8 MFMA
// setprio(0) -> barrier}. Staging of kb+1 spread over phases 0-2 ordered by
// first-use; waits are ONLY vmcnt(6)@ph1 and vmcnt(2)@ph3 - outstanding DMA
// never drains to 0 in the main loop (m218: counted-vs-drain0 = +38..73%;
// all previous rounds were drain-0 per kb and all landed ~340us).
//
// Steady-state per-thread vmem trace (8 stage issues/kb: ph0 B0,B1; ph1
// B2,B3,A0,A2; ph2 A1,A3):  enter ph0 with 2 outstanding (A1,A3 of kb) ->
// ph0 +2 =4 -> ph1 +4 =8, vmcnt(6) retires A1,A3(kb) [needed ph2, 2 barriers
// later] -> ph2 +2 =8 -> ph3 vmcnt(2) retires B0..B3,A0,A2(kb+1) [needed
// kb+1 ph0]. Every retired unit had >=2 phases (~1100cy) in flight.
// Slot-write safety: each stage issue is >=1 barrier after the last ds_read
// of its slot (checked per unit); reads of a phase complete before that
// phase's 2nd barrier, writes for the slot are issued after it.
__global__ __launch_bounds__(512, 2) void gemm_fp8(const unsigned char* __restrict__ A,
                                                   const unsigned char* __restrict__ B,
                                                   const float* __restrict__ sinv,
                                                   const float* __restrict__ xscale,
                                                   float* __restrict__ C) {
    constexpr int BM = 256, BN = 256, BK = 128;
    constexpr int NKB = K_IN / BK;  // 32 K-tiles, one weight-scale block each
    // 128 KB: buf p at p*65536; A tile 32 KB (rows 0..255 x 128B, swizzled
    // 16B slots), B tile 32 KB at +32768. 8KB stage unit u = 64 rows.
    extern __shared__ unsigned char smem[];

    const int bn  = blockIdx.x;      // 24 o-tiles (each spans 2 scale blocks)
    const int bm  = blockIdx.y;      // 32 token tiles
    const int tid = threadIdx.x;
    const int lane = tid & 63;
    const int wv   = tid >> 6;
    const int wm   = (wv >> 2) * 128;   // wave M offset in tile
    const int wn   = (wv & 3) * 64;     // wave N offset in tile
    const int G2   = (lane >> 4) * 2;   // k-chunk pair for this lane group

    // ---- staging: linear LDS dest (gload_lds lane rule), swizzle on the
    //      GLOBAL source chunk (rule #21). Slot j of row r holds chunk j^(r&7).
    const int tr = tid >> 3;                  // 64 rows per 8KB unit
    const int kc = (tid & 7) ^ (tr & 7);
    const unsigned char* Ag = A + (size_t)(bm * BM + tr) * K_IN + kc * 16;
    const unsigned char* Bgs = B + (size_t)(bn * BN + tr) * K_IN + kc * 16;
    const int ldst = tid * 16;

    // ---- fragment-read constants (r&7 == lane&7 for all fragment rows)
    const int rA  = lane & 15;
    const int cs0 = ((G2    ) ^ (lane & 7)) * 16;
    const int cs1 = ((G2 + 1) ^ (lane & 7)) * 16;

    const float* srow = sinv + (size_t)(bn * 2 + (wn >> 7)) * NKB;

    union F { i32x8 v; int4 h[2]; };
    f32x4 acc[8][4] = {};
    F a[4], b0, b1, b2, b3;
    float s_prev = srow[0];

#define STG_A(p_, u_, k0_) load_lds_16(Ag + (size_t)(u_) * 64 * K_IN + (k0_), \
        smem + (size_t)(p_) * 65536 + (u_) * 8192 + ldst)
#define STG_B(p_, u_, k0_) load_lds_16(Bgs + (size_t)(u_) * 64 * K_IN + (k0_), \
        smem + (size_t)(p_) * 65536 + 32768 + (u_) * 8192 + ldst)

#define LDA_(d_, i_) { const unsigned char* q_ = pA + (wm + (i_) * 16 + rA) * 128; \
    (d_).h[0] = *(const int4*)(q_ + cs0); (d_).h[1] = *(const int4*)(q_ + cs1); }
#define LDB_(d_, j_) { const unsigned char* q_ = pB + (wn + (j_) * 16 + rA) * 128; \
    (d_).h[0] = *(const int4*)(q_ + cs0); (d_).h[1] = *(const int4*)(q_ + cs1); }

#define MFMA(i_, j_, af_, bf_)                                               \
    acc[i_][j_] = __builtin_amdgcn_mfma_scale_f32_16x16x128_f8f6f4(          \
        (af_).v, (bf_).v, acc[i_][j_], 0 /*A=fp8*/, 0 /*B=fp8*/,             \
        0, 0x7f7f7f7f, 0, 0x7f7f7f7f);

#define FENCE() asm volatile("" ::: "memory")
#define BARRIER() do { FENCE(); __builtin_amdgcn_s_barrier(); FENCE(); } while (0)
#define VMW(n_) do { __builtin_amdgcn_sched_barrier(0);                      \
    asm volatile("s_waitcnt vmcnt(" #n_ ")" ::: "memory");                   \
    __builtin_amdgcn_sched_barrier(0); } while (0)
#define LGKM0() do { asm volatile("s_waitcnt lgkmcnt(0)" ::: "memory");      \
    __builtin_amdgcn_sched_barrier(0); } while (0)

    // ---- prologue: kb0 into buf0, issued in steady-state order:
    //      6 first-needed units, then A u1,u3; vmcnt(2) retires the 6.
    STG_B(0, 0, 0); STG_B(0, 1, 0); STG_B(0, 2, 0); STG_B(0, 3, 0);
    STG_A(0, 0, 0); STG_A(0, 2, 0);
    STG_A(0, 1, 0); STG_A(0, 3, 0);
    VMW(2);
    BARRIER();

    for (int kb = 0; kb < NKB; ++kb) {
        const unsigned char* pA = smem + (size_t)(kb & 1) * 65536;
        const unsigned char* pB = pA + 32768;
        const int    pn  = (kb + 1) & 1;
        const size_t nk0 = (size_t)((kb + 1) & 31) * BK;  // tail wraps; slots unread
        const float s_cur = srow[kb];
        const float rr = s_prev / s_cur;   // exactly 1.0 at kb==0
        s_prev = s_cur;

        // ---------- phase 0: i0..3 x j0,1  (+stage B u0,u1 of kb+1)
        LDA_(a[0], 0) LDA_(a[1], 1) LDA_(a[2], 2) LDA_(a[3], 3)
        LDB_(b0, 0) LDB_(b1, 1)
        STG_B(pn, 0, nk0); STG_B(pn, 1, nk0);
#pragma unroll
        for (int i = 0; i < 4; ++i) { acc[i][0] *= rr; acc[i][1] *= rr; }
        BARRIER(); LGKM0();
        __builtin_amdgcn_s_setprio(1);
#pragma unroll
        for (int i = 0; i < 4; ++i) { MFMA(i, 0, a[i], b0); MFMA(i, 1, a[i], b1); }
        __builtin_amdgcn_s_setprio(0);
        BARRIER();

        // ---------- phase 1: i0..3 x j2,3  (+stage B u2,u3, A u0,u2)
        LDB_(b2, 2) LDB_(b3, 3)
        STG_B(pn, 2, nk0); STG_B(pn, 3, nk0);
        STG_A(pn, 0, nk0); STG_A(pn, 2, nk0);
#pragma unroll
        for (int i = 0; i < 4; ++i) { acc[i][2] *= rr; acc[i][3] *= rr; }
        VMW(6);   // retires A u1,u3 of kb (needed next phase, 2 barriers away)
        BARRIER(); LGKM0();
        __builtin_amdgcn_s_setprio(1);
#pragma unroll
        for (int i = 0; i < 4; ++i) { MFMA(i, 2, a[i], b2); MFMA(i, 3, a[i], b3); }
        __builtin_amdgcn_s_setprio(0);
        BARRIER();

        // ---------- phase 2: i4..7 x j2,3  (+stage A u1,u3)
        LDA_(a[0], 4) LDA_(a[1], 5) LDA_(a[2], 6) LDA_(a[3], 7)
        STG_A(pn, 1, nk0); STG_A(pn, 3, nk0);
#pragma unroll
        for (int i = 0; i < 4; ++i) { acc[4 + i][2] *= rr; acc[4 + i][3] *= rr; }
        BARRIER(); LGKM0();
        __builtin_amdgcn_s_setprio(1);
#pragma unroll
        for (int i = 0; i < 4; ++i) { MFMA(4 + i, 2, a[i], b2); MFMA(4 + i, 3, a[i], b3); }
        __builtin_amdgcn_s_setprio(0);
        BARRIER();

        // ---------- phase 3: i4..7 x j0,1  (b0,b1 reloaded)
        LDB_(b0, 0) LDB_(b1, 1)
#pragma unroll
        for (int i = 0; i < 4; ++i) { acc[4 + i][0] *= rr; acc[4 + i][1] *= rr; }
        VMW(2);   // retires B u0..3 + A u0,u2 of kb+1 (needed kb+1 ph0)
        BARRIER(); LGKM0();
        __builtin_amdgcn_s_setprio(1);
#pragma unroll
        for (int i = 0; i < 4; ++i) { MFMA(4 + i, 0, a[i], b0); MFMA(4 + i, 1, a[i], b1); }
        __builtin_amdgcn_s_setprio(0);
        BARRIER();
    }
    // drain dangling tail prefetch DMA before LDS handoff / kernel exit
    VMW(0);

    // epilogue: D col=lane&15, row=(lane>>4)*4+reg; final scale = s_last * xs[token]
#pragma unroll
    for (int i = 0; i < 8; ++i) {
#pragma unroll
        for (int r = 0; r < 4; ++r) {
            const int m_g = bm * BM + wm + i * 16 + (lane >> 4) * 4 + r;
            const float f = xscale[m_g] * s_prev;
            float* crow = C + (size_t)m_g * O_OUT + bn * BN + wn;
#pragma unroll
            for (int j = 0; j < 4; ++j)
                crow[j * 16 + (lane & 15)] = acc[i][j][r] * f;
        }
    }
#undef STG_A
#undef STG_B
#undef LDA_
#undef LDB_
#undef MFMA
#undef FENCE
#undef BARRIER
#undef VMW
#undef LGKM0
}

// ---------- launch ----------
extern "C" void kernel_launch(void* const* d_in, const int* in_sizes, int n_in,
                              void* d_out, int out_size, void* d_ws, size_t ws_size,
                              hipStream_t stream) {
    const float* x    = (const float*)d_in[0];
    const float* w    = (const float*)d_in[1];
    const float* sinv = (const float*)d_in[2];
    float* out = (float*)d_out;

    char* ws = (char*)d_ws;
    uint32* xq = (uint32*)ws;                                   // 32 MB (fp8 bytes)
    uint32* wq = (uint32*)(ws + (size_t)T_TOK * K_IN);          // 24 MB
    float* xscale = (float*)(ws + (size_t)T_TOK * K_IN
                                + (size_t)O_OUT * K_IN);        // 32 KB

    quant_x<<<T_TOK, 256, 0, stream>>>(x, xq, xscale);
    quant_w<<<(O_OUT * K_IN) / (4 * 256), 256, 0, stream>>>(w, wq);
    dim3 grid(O_OUT / 256, T_TOK / 256);   // (24, 32)
    gemm_fp8<<<grid, 512, 131072 /*dynamic LDS: 2x(32K A + 32K B)*/, stream>>>(
        (const unsigned char*)xq, (const unsigned char*)wq, sinv, xscale, out);
}